// Round 1
// baseline (446.694 us; speedup 1.0000x reference)
//
#include <hip/hip_runtime.h>
#include <stdint.h>

// Problem constants (fixed by reference: features (16384, 512) fp32)
#define NROWS 16384
#define KDIM  512
#define BM 128
#define BN 128
#define BK 32
#define CT 4        // column tiles per block
#define NCHUNK 32   // NROWS / (BN*CT)
#define INV_T 14.285714285714286f  // 1/0.07

typedef __bf16 bf16x8 __attribute__((ext_vector_type(8)));
typedef float  f32x4  __attribute__((ext_vector_type(4)));
typedef unsigned short u16x8 __attribute__((ext_vector_type(8)));

// ---- async global->LDS, 16B per lane (CK-style casts) ----
__device__ __forceinline__ void gload_lds16(const void* gptr, void* lptr) {
    uint32_t loff = (uint32_t)(uintptr_t)lptr;             // low 32 bits of generic LDS ptr = LDS offset
    loff = __builtin_amdgcn_readfirstlane(loff);           // wave-uniform base (HW adds lane*16)
    __builtin_amdgcn_global_load_lds(
        (const uint32_t __attribute__((address_space(1)))*)(uintptr_t)gptr,
        (uint32_t __attribute__((address_space(3)))*)(uintptr_t)loff,
        16, 0, 0);
}

// ---- kernel 1: L2 normalize + scale + cast to bf16. One wave per row. ----
__global__ void k_norm(const float* __restrict__ X, __bf16* __restrict__ Y, float scale) {
    const int row  = blockIdx.x * 4 + (threadIdx.x >> 6);
    const int lane = threadIdx.x & 63;
    const float* xr = X + (size_t)row * KDIM + lane * 8;
    float4 a = *(const float4*)xr;
    float4 b = *(const float4*)(xr + 4);
    float ss = a.x*a.x + a.y*a.y + a.z*a.z + a.w*a.w
             + b.x*b.x + b.y*b.y + b.z*b.z + b.w*b.w;
    #pragma unroll
    for (int off = 1; off < 64; off <<= 1) ss += __shfl_xor(ss, off);
    const float s = scale / fmaxf(sqrtf(ss), 1e-12f);
    __bf16 o[8];
    o[0] = (__bf16)(a.x * s); o[1] = (__bf16)(a.y * s);
    o[2] = (__bf16)(a.z * s); o[3] = (__bf16)(a.w * s);
    o[4] = (__bf16)(b.x * s); o[5] = (__bf16)(b.y * s);
    o[6] = (__bf16)(b.z * s); o[7] = (__bf16)(b.w * s);
    *(u16x8*)(Y + (size_t)row * KDIM + lane * 8) = *(const u16x8*)o;
}

// ---- kernel 2: fused GEMM + exp + row-sum. m97 structure, 128x128 tile. ----
// A = f1n (scaled by 1/T), B = f2n, both [NROWS][KDIM] bf16 row-major.
// Block (bx, chunk): rows [bx*128,+128), cols [chunk*512,+512) as 4 x 128-col tiles.
__global__ __launch_bounds__(256) void k_gemm_expsum(
    const __bf16* __restrict__ A, const __bf16* __restrict__ B,
    float* __restrict__ S_part) {
    __shared__ __align__(16) __bf16 At[BM][BK];   // 8KB
    __shared__ __align__(16) __bf16 Bt[BN][BK];   // 8KB
    __shared__ float rowsum[2][BM];               // 1KB

    const int tid  = threadIdx.x;
    const int lane = tid & 63;
    const int w    = tid >> 6;        // wave 0..3
    const int wr   = w >> 1, wc = w & 1;
    const int brow = blockIdx.x * BM;
    const int chunk = blockIdx.y;

    // staging map: lane covers At[w*16 + lane/4][(lane&3)*8 ..+8] (16B), 2 issues (rows +0, +64)
    const int srow = w * 16 + (lane >> 2);
    const int scol = (lane & 3) * 8;
    const int frow = lane & 15;            // MFMA fragment row/col
    const int fk   = (lane >> 4) * 8;      // MFMA fragment k-offset

    float rowacc = 0.f;                    // thread t<128 owns row brow+t

    for (int ct = 0; ct < CT; ++ct) {
        const int bcol = (chunk * CT + ct) * BN;
        f32x4 acc[4][4] = {};

        for (int ks = 0; ks < KDIM / BK; ++ks) {
            const int k0 = ks * BK;
            __syncthreads();  // previous reads done before overwrite
            gload_lds16(&A[(size_t)(brow +      srow) * KDIM + k0 + scol], &At[w * 16][0]);
            gload_lds16(&A[(size_t)(brow + 64 + srow) * KDIM + k0 + scol], &At[64 + w * 16][0]);
            gload_lds16(&B[(size_t)(bcol +      srow) * KDIM + k0 + scol], &Bt[w * 16][0]);
            gload_lds16(&B[(size_t)(bcol + 64 + srow) * KDIM + k0 + scol], &Bt[64 + w * 16][0]);
            asm volatile("s_waitcnt vmcnt(0)" ::: "memory");
            __syncthreads();

            bf16x8 af[4], bf[4];
            #pragma unroll
            for (int m = 0; m < 4; ++m)
                af[m] = *(const bf16x8*)&At[wr * 64 + m * 16 + frow][fk];
            #pragma unroll
            for (int n = 0; n < 4; ++n)
                bf[n] = *(const bf16x8*)&Bt[wc * 64 + n * 16 + frow][fk];
            #pragma unroll
            for (int m = 0; m < 4; ++m)
                #pragma unroll
                for (int n = 0; n < 4; ++n)
                    acc[m][n] = __builtin_amdgcn_mfma_f32_16x16x32_bf16(
                        af[m], bf[n], acc[m][n], 0, 0, 0);
        }

        // epilogue: exp + row-reduce. C/D layout: col = lane&15, row = (lane>>4)*4 + reg
        float rs[4][4];
        #pragma unroll
        for (int m = 0; m < 4; ++m)
            #pragma unroll
            for (int r = 0; r < 4; ++r) {
                float s = 0.f;
                #pragma unroll
                for (int n = 0; n < 4; ++n) s += __expf(acc[m][n][r]);
                rs[m][r] = s;
            }
        #pragma unroll
        for (int off = 8; off >= 1; off >>= 1)
            #pragma unroll
            for (int m = 0; m < 4; ++m)
                #pragma unroll
                for (int r = 0; r < 4; ++r)
                    rs[m][r] += __shfl_xor(rs[m][r], off);

        if ((lane & 15) == 0) {
            const int rbase = wr * 64 + (lane >> 4) * 4;
            #pragma unroll
            for (int m = 0; m < 4; ++m)
                #pragma unroll
                for (int r = 0; r < 4; ++r)
                    rowsum[wc][rbase + m * 16 + r] = rs[m][r];
        }
        __syncthreads();
        if (tid < BM) rowacc += rowsum[0][tid] + rowsum[1][tid];
    }

    if (tid < BM) S_part[(size_t)chunk * NROWS + brow + tid] = rowacc;
}

// ---- kernel 3: diagonal logits. One wave per row. ----
__global__ void k_diag(const __bf16* __restrict__ A, const __bf16* __restrict__ B,
                       float* __restrict__ diag) {
    const int row  = blockIdx.x * 4 + (threadIdx.x >> 6);
    const int lane = threadIdx.x & 63;
    const bf16x8 va = *(const bf16x8*)(A + (size_t)row * KDIM + lane * 8);
    const bf16x8 vb = *(const bf16x8*)(B + (size_t)row * KDIM + lane * 8);
    float d = 0.f;
    #pragma unroll
    for (int i = 0; i < 8; ++i) d += (float)va[i] * (float)vb[i];
    #pragma unroll
    for (int off = 1; off < 64; off <<= 1) d += __shfl_xor(d, off);
    if (lane == 0) diag[row] = d;
}

// ---- kernel 4: per-row loss + block partial sums (deterministic) ----
__global__ void k_loss(const float* __restrict__ S_part, const float* __restrict__ diag,
                       float* __restrict__ partial) {
    const int g = blockIdx.x * 256 + threadIdx.x;
    float S = 0.f;
    #pragma unroll
    for (int c = 0; c < NCHUNK; ++c) S += S_part[(size_t)c * NROWS + g];
    float v = logf(S) - diag[g];
    __shared__ float wsum[4];
    #pragma unroll
    for (int off = 1; off < 64; off <<= 1) v += __shfl_xor(v, off);
    if ((threadIdx.x & 63) == 0) wsum[threadIdx.x >> 6] = v;
    __syncthreads();
    if (threadIdx.x == 0) partial[blockIdx.x] = wsum[0] + wsum[1] + wsum[2] + wsum[3];
}

__global__ void k_final(const float* __restrict__ partial, float* __restrict__ out) {
    float v = partial[threadIdx.x];
    #pragma unroll
    for (int off = 1; off < 64; off <<= 1) v += __shfl_xor(v, off);
    if (threadIdx.x == 0) out[0] = v * (1.0f / (float)NROWS);
}

extern "C" void kernel_launch(void* const* d_in, const int* in_sizes, int n_in,
                              void* d_out, int out_size, void* d_ws, size_t ws_size,
                              hipStream_t stream) {
    const float* f1 = (const float*)d_in[0];
    const float* f2 = (const float*)d_in[1];
    float* out = (float*)d_out;

    char* ws = (char*)d_ws;
    __bf16* f1n   = (__bf16*)(ws);                       // 16 MB
    __bf16* f2n   = (__bf16*)(ws + (16u << 20));         // 16 MB
    float* S_part = (float*)(ws + (32u << 20));          // 2 MB  [NCHUNK][NROWS]
    float* diag   = (float*)(ws + (34u << 20));          // 64 KB
    float* part   = (float*)(ws + (34u << 20) + (1u << 16)); // 256 B

    k_norm<<<dim3(NROWS / 4), dim3(256), 0, stream>>>(f1, f1n, INV_T);
    k_norm<<<dim3(NROWS / 4), dim3(256), 0, stream>>>(f2, f2n, 1.0f);
    k_gemm_expsum<<<dim3(NROWS / BM, NCHUNK), dim3(256), 0, stream>>>(f1n, f2n, S_part);
    k_diag<<<dim3(NROWS / 4), dim3(256), 0, stream>>>(f1n, f2n, diag);
    k_loss<<<dim3(NROWS / 256), dim3(256), 0, stream>>>(S_part, diag, part);
    k_final<<<dim3(1), dim3(64), 0, stream>>>(part, out);
}

// Round 3
// 370.087 us; speedup vs baseline: 1.2070x; 1.2070x over previous
//
#include <hip/hip_runtime.h>
#include <stdint.h>

#define NROWS 16384
#define KDIM  512
#define BM 256
#define BN 256
#define CT 2
#define NCHUNK 32           // 16384 / (BN*CT)
#define NPHASE 16           // K-halves of 32 elems: 512/32
#define INV_T 14.285714285714286f
#define LOG2E 1.4426950408889634f
#define LN2   0.6931471805599453f

typedef __bf16 bf16x8 __attribute__((ext_vector_type(8)));
typedef float  f32x4  __attribute__((ext_vector_type(4)));
typedef unsigned short u16x8 __attribute__((ext_vector_type(8)));

// async global->LDS, 16B/lane; LDS dest = wave-uniform base + lane*16
__device__ __forceinline__ void gload_lds16(const void* gptr, void* lptr) {
    uint32_t loff = (uint32_t)(uintptr_t)lptr;
    loff = __builtin_amdgcn_readfirstlane(loff);
    __builtin_amdgcn_global_load_lds(
        (const uint32_t __attribute__((address_space(1)))*)(uintptr_t)gptr,
        (uint32_t __attribute__((address_space(3)))*)(uintptr_t)loff,
        16, 0, 0);
}

// ---- kernel 1: L2 normalize + scale + bf16 cast, writing K-half panel layout:
// panel[kh][row][granule], kh=k/32, granule position = (g_logical ^ (row&3)), 16B granules.
__global__ void k_norm(const float* __restrict__ X, char* __restrict__ Y, float scale) {
    const int row  = blockIdx.x * 4 + (threadIdx.x >> 6);
    const int lane = threadIdx.x & 63;
    const float* xr = X + (size_t)row * KDIM + lane * 8;
    float4 a = *(const float4*)xr;
    float4 b = *(const float4*)(xr + 4);
    float ss = a.x*a.x + a.y*a.y + a.z*a.z + a.w*a.w
             + b.x*b.x + b.y*b.y + b.z*b.z + b.w*b.w;
    #pragma unroll
    for (int off = 1; off < 64; off <<= 1) ss += __shfl_xor(ss, off);
    const float s = scale / fmaxf(sqrtf(ss), 1e-12f);
    __bf16 o[8];
    o[0] = (__bf16)(a.x * s); o[1] = (__bf16)(a.y * s);
    o[2] = (__bf16)(a.z * s); o[3] = (__bf16)(a.w * s);
    o[4] = (__bf16)(b.x * s); o[5] = (__bf16)(b.y * s);
    o[6] = (__bf16)(b.z * s); o[7] = (__bf16)(b.w * s);
    // lane l holds logical granule l: kh = l>>2, g = l&3; swizzle with row&3
    char* dst = Y + ((size_t)(lane >> 2) * NROWS + row) * 64
                  + (((lane & 3) ^ (row & 3)) << 4);
    *(u16x8*)dst = *(const u16x8*)o;
}

// ---- kernel 2: fused GEMM + exp2 + row-sum. 256x256 tile, BK=64 (2 K-halves/tile),
// 8 waves (2M x 4N), 4-slot LDS ring, counted vmcnt (steady state keeps 4 loads in flight).
__global__ __launch_bounds__(512, 1) void k_gemm(const char* __restrict__ A,
                                                 const char* __restrict__ B,
                                                 float* __restrict__ S_part) {
    __shared__ __align__(16) char L[4 * 32768];   // 4 slots x (A-half 16KB + B-half 16KB)
    __shared__ float rowsum[4][BM];

    const int tid  = threadIdx.x;
    const int lane = tid & 63;
    const int w    = tid >> 6;           // 0..7
    const int wr   = w >> 2, wc = w & 3; // 2 x 4 wave grid
    const int frow = lane & 15;
    const int q    = lane >> 4;
    // XCD-aware swizzle: 2048 blocks, 8 XCDs, 2048%8==0
    const int bid   = blockIdx.x;
    const int swzb  = (bid & 7) * 256 + (bid >> 3);
    const int brow  = (swzb & 63) * BM;
    const int chunk = swzb >> 6;         // 0..31

    // per-thread ds_read byte offsets within a slot (granule XOR swizzle)
    const int swz  = (q ^ (frow & 3)) << 4;
    const int aoff = (wr * 128 + frow) * 64 + swz;          // + m*1024
    const int boff = 16384 + (wc * 64 + frow) * 64 + swz;   // + n*1024

#define STAGE(h_, s_) do {                                               \
        const char* ga_ = A + (size_t)((h_) * NROWS + brow) * 64 + tid * 16; \
        const char* gb_ = B + (size_t)((h_) * NROWS + bcol) * 64 + tid * 16; \
        char* la_ = L + (s_) * 32768 + tid * 16;                         \
        gload_lds16(ga_,        la_);                                    \
        gload_lds16(ga_ + 8192, la_ + 8192);                             \
        gload_lds16(gb_,        la_ + 16384);                            \
        gload_lds16(gb_ + 8192, la_ + 24576);                            \
    } while (0)

    float rowacc = 0.f;
    for (int ct = 0; ct < CT; ++ct) {
        const int bcol = (chunk * CT + ct) * BN;
        f32x4 acc[8][4] = {};

        // prologue: stage H0,H1; wait for H0 (leave H1's 4 loads in flight)
        STAGE(0, 0);
        STAGE(1, 1);
        asm volatile("s_waitcnt vmcnt(4)" ::: "memory");
        __builtin_amdgcn_s_barrier();
        __builtin_amdgcn_sched_barrier(0);

        #pragma unroll
        for (int h = 0; h < NPHASE; ++h) {
            if (h < NPHASE - 2) STAGE(h + 2, (h + 2) & 3);
            const char* sl = L + (h & 3) * 32768;
            bf16x8 a[8], b[4];
            #pragma unroll
            for (int m = 0; m < 8; ++m) a[m] = *(const bf16x8*)(sl + aoff + m * 1024);
            #pragma unroll
            for (int n = 0; n < 4; ++n) b[n] = *(const bf16x8*)(sl + boff + n * 1024);
            __builtin_amdgcn_s_setprio(1);
            #pragma unroll
            for (int m = 0; m < 8; ++m)
                #pragma unroll
                for (int n = 0; n < 4; ++n)
                    acc[m][n] = __builtin_amdgcn_mfma_f32_16x16x32_bf16(
                        a[m], b[n], acc[m][n], 0, 0, 0);
            __builtin_amdgcn_s_setprio(0);
            // H(h+1) must be landed before next phase reads it; keep H(h+2) in flight
            if (h < NPHASE - 2)      asm volatile("s_waitcnt vmcnt(4)" ::: "memory");
            else if (h == NPHASE - 2) asm volatile("s_waitcnt vmcnt(0)" ::: "memory");
            __builtin_amdgcn_s_barrier();
            __builtin_amdgcn_sched_barrier(0);
        }

        // epilogue: logits are log2-scaled (A carries 1/T*log2e) -> exp2
        // C/D: row = (lane>>4)*4 + r (A side), col = lane&15 (B side)
        float rs[8][4];
        #pragma unroll
        for (int m = 0; m < 8; ++m)
            #pragma unroll
            for (int r = 0; r < 4; ++r)
                rs[m][r] = __builtin_amdgcn_exp2f(acc[m][0][r])
                         + __builtin_amdgcn_exp2f(acc[m][1][r])
                         + __builtin_amdgcn_exp2f(acc[m][2][r])
                         + __builtin_amdgcn_exp2f(acc[m][3][r]);
        #pragma unroll
        for (int off = 8; off >= 1; off >>= 1)
            #pragma unroll
            for (int m = 0; m < 8; ++m)
                #pragma unroll
                for (int r = 0; r < 4; ++r)
                    rs[m][r] += __shfl_xor(rs[m][r], off);
        if ((lane & 15) == 0) {
            const int rb = wr * 128 + q * 4;
            #pragma unroll
            for (int m = 0; m < 8; ++m)
                #pragma unroll
                for (int r = 0; r < 4; ++r)
                    rowsum[wc][rb + m * 16 + r] = rs[m][r];
        }
        __syncthreads();
        if (tid < BM)
            rowacc += rowsum[0][tid] + rowsum[1][tid] + rowsum[2][tid] + rowsum[3][tid];
        __syncthreads();
    }
#undef STAGE
    if (tid < BM) S_part[(size_t)chunk * NROWS + brow + tid] = rowacc;
}

// ---- kernel 3: diagonal logits (log2-scaled). Panel layout; A/B rows share the
// same per-row granule permutation, so a linear elementwise dot is correct.
__global__ void k_diag(const char* __restrict__ A, const char* __restrict__ B,
                       float* __restrict__ diag) {
    const int row  = blockIdx.x * 4 + (threadIdx.x >> 6);
    const int lane = threadIdx.x & 63;
    const size_t off = ((size_t)(lane >> 2) * NROWS + row) * 64 + ((lane & 3) << 4);
    const bf16x8 va = *(const bf16x8*)(A + off);
    const bf16x8 vb = *(const bf16x8*)(B + off);
    float d = 0.f;
    #pragma unroll
    for (int i = 0; i < 8; ++i) d += (float)va[i] * (float)vb[i];
    #pragma unroll
    for (int off2 = 1; off2 < 64; off2 <<= 1) d += __shfl_xor(d, off2);
    if (lane == 0) diag[row] = d;
}

// ---- kernel 4: per-row loss + deterministic block partials
__global__ void k_loss(const float* __restrict__ S_part, const float* __restrict__ diag,
                       float* __restrict__ partial) {
    const int g = blockIdx.x * 256 + threadIdx.x;
    float S = 0.f;
    #pragma unroll
    for (int c = 0; c < NCHUNK; ++c) S += S_part[(size_t)c * NROWS + g];
    float v = logf(S) - diag[g] * LN2;   // diag is log2-scaled
    __shared__ float wsum[4];
    #pragma unroll
    for (int off = 1; off < 64; off <<= 1) v += __shfl_xor(v, off);
    if ((threadIdx.x & 63) == 0) wsum[threadIdx.x >> 6] = v;
    __syncthreads();
    if (threadIdx.x == 0) partial[blockIdx.x] = wsum[0] + wsum[1] + wsum[2] + wsum[3];
}

__global__ void k_final(const float* __restrict__ partial, float* __restrict__ out) {
    float v = partial[threadIdx.x];
    #pragma unroll
    for (int off = 1; off < 64; off <<= 1) v += __shfl_xor(v, off);
    if (threadIdx.x == 0) out[0] = v * (1.0f / (float)NROWS);
}

extern "C" void kernel_launch(void* const* d_in, const int* in_sizes, int n_in,
                              void* d_out, int out_size, void* d_ws, size_t ws_size,
                              hipStream_t stream) {
    const float* f1 = (const float*)d_in[0];
    const float* f2 = (const float*)d_in[1];
    float* out = (float*)d_out;

    char* ws = (char*)d_ws;
    char*  f1p   = ws;                                  // 16 MB panel
    char*  f2p   = ws + (16u << 20);                    // 16 MB panel
    float* S_part = (float*)(ws + (32u << 20));         // 2 MB [NCHUNK][NROWS]
    float* diag   = (float*)(ws + (34u << 20));         // 64 KB
    float* part   = (float*)(ws + (34u << 20) + (1u << 16)); // 256 B

    k_norm<<<dim3(NROWS / 4), dim3(256), 0, stream>>>(f1, f1p, INV_T * LOG2E);
    k_norm<<<dim3(NROWS / 4), dim3(256), 0, stream>>>(f2, f2p, 1.0f);
    k_gemm<<<dim3((NROWS / BM) * NCHUNK), dim3(512), 0, stream>>>(f1p, f2p, S_part);
    k_diag<<<dim3(NROWS / 4), dim3(256), 0, stream>>>(f1p, f2p, diag);
    k_loss<<<dim3(NROWS / 256), dim3(256), 0, stream>>>(S_part, diag, part);
    k_final<<<dim3(1), dim3(64), 0, stream>>>(part, out);
}